// Round 10
// baseline (665.448 us; speedup 1.0000x reference)
//
#include <hip/hip_runtime.h>
#include <hip/hip_bf16.h>

namespace {
constexpr int NB = 128;   // batch
constexpr int NL = 2048;  // seq len
constexpr int ND = 128;   // emb dim
constexpr int NH = 256;   // hidden
constexpr int NO = 128;   // encoder out dim
constexpr int NK = 64;    // top-k
constexpr int MCAP = 192; // candidate cap per batch
constexpr int HTHR = 96;  // histogram cumulative threshold
constexpr int BLOOP = 8;  // batches per score block
constexpr float MASK_FILL_F = -1e9f;
constexpr float LN_EPS_F = 1e-5f;
}

typedef __attribute__((ext_vector_type(8))) short bf16x8;
typedef __attribute__((ext_vector_type(4))) float f32x4;

__device__ __forceinline__ unsigned short bf16rne(float x) {
  unsigned u = __float_as_uint(x);
  return (unsigned short)((u + 0x7FFFu + ((u >> 16) & 1u)) >> 16);
}

// ---------- fused prep: W1 seq-slab -> bf16T | P[l,h] | T[b,h] ----------
// (R8 lesson: single-row contrib blocks, 2304 total, 8 blocks/CU TLP)
__global__ __launch_bounds__(256) void k_prep(
    const float* __restrict__ W1, const float* __restrict__ pos,
    const float* __restrict__ tgt, const float* __restrict__ b1,
    unsigned short* __restrict__ W1aT, float* __restrict__ P,
    float* __restrict__ T) {
  const int blk = blockIdx.x, t = threadIdx.x;
  if (blk < ND) {  // W1aT[h][d]: d = blk (0..127), h = t (0..255)
    W1aT[(size_t)t * ND + blk] = bf16rne(W1[(size_t)blk * NH + t]);
    return;
  }
  int r, w_off, add_bias;
  const float* src;
  float* out;
  if (blk < ND + NL) {
    r = blk - ND; src = pos; out = P; w_off = ND; add_bias = 1;
  } else {
    r = blk - (ND + NL); src = tgt; out = T; w_off = 2 * ND; add_bias = 0;
  }
  __shared__ float row[ND];
  if (t < ND) row[t] = src[(size_t)r * ND + t];
  __syncthreads();
  float acc = add_bias ? b1[t] : 0.0f;
#pragma unroll 8
  for (int d = 0; d < ND; ++d)
    acc = fmaf(row[d], W1[(size_t)(w_off + d) * NH + t], acc);
  out[(size_t)r * NH + t] = acc;
}

// ---------- approximate scores (identical to R9 / validated 145us config) ----------
__global__ __launch_bounds__(512, 2) void k_scores_mfma(
    const float* __restrict__ seq, const int* __restrict__ mask,
    const unsigned short* __restrict__ W1aT, const float* __restrict__ w2,
    const float* __restrict__ b2, const float* __restrict__ b1,
    const float* __restrict__ T, float* __restrict__ scores) {
  const int l0 = blockIdx.x * 128;
  const int b0 = blockIdx.y * BLOOP;
  const int t = threadIdx.x;
  const int lane = t & 63;
  const int w = t >> 6;      // 0..7
  const int wh = w & 3;      // h-block
  const int wl = w >> 2;     // l-block
  const int lh = lane & 15;
  const int kq = lane >> 4;  // 0..3

  __shared__ unsigned short sSeq[2][128 * 128];  // 2 x 32 KB dbuf, swizzled
  __shared__ float sRed[4][128];

  bf16x8 a[4][4];
#pragma unroll
  for (int ks = 0; ks < 4; ++ks)
#pragma unroll
    for (int mt = 0; mt < 4; ++mt)
      a[ks][mt] = *(const bf16x8*)(
          W1aT + (size_t)(wh * 64 + mt * 16 + lh) * ND + ks * 32 + kq * 8);

  float4 wv[4], b1v[4];
#pragma unroll
  for (int mt = 0; mt < 4; ++mt) {
    wv[mt] = *(const float4*)(w2 + wh * 64 + mt * 16 + kq * 4);
    b1v[mt] = *(const float4*)(b1 + wh * 64 + mt * 16 + kq * 4);
  }
  const float b2v = b2[0];

  ushort4 pf[8];
  auto prefetch = [&](int bb) {
    const float4* g = (const float4*)(seq + ((size_t)bb * NL + l0) * ND);
#pragma unroll
    for (int i = 0; i < 8; ++i) {
      const float4 f = g[t + i * 512];
      pf[i].x = bf16rne(f.x); pf[i].y = bf16rne(f.y);
      pf[i].z = bf16rne(f.z); pf[i].w = bf16rne(f.w);
    }
  };
  auto commit = [&](unsigned short* dst) {
#pragma unroll
    for (int i = 0; i < 8; ++i) {
      const int v = t + i * 512;
      const int row = v >> 5;
      const int c8 = (v & 31) * 8;
      const int off = (row << 8) + (c8 ^ ((row & 15) << 4));
      *(ushort4*)((char*)dst + off) = pf[i];
    }
  };

  prefetch(b0);
  commit((unsigned short*)sSeq[0]);
  __syncthreads();

#pragma unroll 1
  for (int j = 0; j < BLOOP; ++j) {
    const int b = b0 + j;
    unsigned short* cSeq = (unsigned short*)sSeq[j & 1];
    unsigned short* nSeq = (unsigned short*)sSeq[(j & 1) ^ 1];

    if (j + 1 < BLOOP) prefetch(b + 1);

    float4 Tv[4];
#pragma unroll
    for (int mt = 0; mt < 4; ++mt)
      Tv[mt] = *(const float4*)(T + (size_t)b * NH + wh * 64 + mt * 16 + kq * 4);

    f32x4 acc[4][4];
#pragma unroll
    for (int mt = 0; mt < 4; ++mt)
#pragma unroll
      for (int nt = 0; nt < 4; ++nt) acc[mt][nt] = (f32x4){0.f, 0.f, 0.f, 0.f};

#pragma unroll
    for (int ks = 0; ks < 4; ++ks) {
      bf16x8 Bf[4];
#pragma unroll
      for (int nt = 0; nt < 4; ++nt) {
        const int row = wl * 64 + nt * 16 + lh;
        const int off = (row << 8) + (((ks << 6) + (kq << 4)) ^ ((row & 15) << 4));
        Bf[nt] = *(const bf16x8*)((const char*)cSeq + off);
      }
#pragma unroll
      for (int mt = 0; mt < 4; ++mt)
#pragma unroll
        for (int nt = 0; nt < 4; ++nt)
          acc[mt][nt] = __builtin_amdgcn_mfma_f32_16x16x32_bf16(
              a[ks][mt], Bf[nt], acc[mt][nt], 0, 0, 0);
    }
    __syncthreads();
    if (j + 1 < BLOOP) commit(nSeq);

    float p[4] = {0.f, 0.f, 0.f, 0.f};
#pragma unroll
    for (int mt = 0; mt < 4; ++mt) {
#pragma unroll
      for (int nt = 0; nt < 4; ++nt) {
        float z;
        z = acc[mt][nt][0] + Tv[mt].x + b1v[mt].x; p[nt] = fmaf(fmaxf(z, 0.f), wv[mt].x, p[nt]);
        z = acc[mt][nt][1] + Tv[mt].y + b1v[mt].y; p[nt] = fmaf(fmaxf(z, 0.f), wv[mt].y, p[nt]);
        z = acc[mt][nt][2] + Tv[mt].z + b1v[mt].z; p[nt] = fmaf(fmaxf(z, 0.f), wv[mt].z, p[nt]);
        z = acc[mt][nt][3] + Tv[mt].w + b1v[mt].w; p[nt] = fmaf(fmaxf(z, 0.f), wv[mt].w, p[nt]);
      }
    }
#pragma unroll
    for (int nt = 0; nt < 4; ++nt) {
      float v = p[nt];
      v += __shfl_xor(v, 16);
      v += __shfl_xor(v, 32);
      if (lane < 16) sRed[wh][wl * 64 + nt * 16 + lane] = v;
    }
    __syncthreads();
    if (t < 128) {
      const int l = l0 + t;
      float sc = sRed[0][t] + sRed[1][t] + sRed[2][t] + sRed[3][t] + b2v;
      if (mask[(size_t)b * NL + l] == 0) sc = MASK_FILL_F;
      scores[(size_t)b * NL + l] = sc;
    }
  }
}

// ---------- fused: histogram topM + exact fp32 rescore + rank select + softmax ----------
// one block per batch, 1024 threads (16 waves).
__global__ __launch_bounds__(1024) void k_select3(
    const float* __restrict__ scores, const float* __restrict__ seq,
    const int* __restrict__ mask, const float* __restrict__ W1,
    const float* __restrict__ w2, const float* __restrict__ b2,
    const float* __restrict__ P, const float* __restrict__ T,
    int* __restrict__ idx_sorted, float* __restrict__ attn) {
  const int b = blockIdx.x, t = threadIdx.x;
  __shared__ unsigned hist[4096];       // 16 KB
  __shared__ unsigned chunk[256];
  __shared__ int sB;
  __shared__ unsigned sCntHi, sCntB, sN;
  __shared__ int s_cand[MCAP];
  __shared__ float s_cs[MCAP];
  __shared__ unsigned long long s_key[MCAP];
  __shared__ int sel_l[NK];
  __shared__ float sel_v[NK];
  __shared__ int srt_l[NK];
  __shared__ float srt_v[NK];

  // --- phase A: histogram over monotone keys ---
  for (int i = t; i < 4096; i += 1024) hist[i] = 0;
  if (t == 0) { sCntHi = 0; sCntB = 0; }
  __syncthreads();
  unsigned key2[2];
#pragma unroll
  for (int i = 0; i < 2; ++i) {
    unsigned u = __float_as_uint(scores[(size_t)b * NL + t + i * 1024]);
    u = (u & 0x80000000u) ? ~u : (u | 0x80000000u);
    key2[i] = u;
    atomicAdd(&hist[u >> 20], 1u);
  }
  __syncthreads();
  if (t < 256) {
    unsigned s = 0;
#pragma unroll 4
    for (int j = 0; j < 16; ++j) s += hist[t * 16 + j];
    chunk[t] = s;
  }
  __syncthreads();
  if (t == 0) {
    unsigned cum = 0;
    int c = 255;
    for (; c > 0; --c) {
      if (cum + chunk[c] >= (unsigned)HTHR) break;
      cum += chunk[c];
    }
    int bin = c * 16 + 15;
    for (; bin > c * 16; --bin) {
      if (cum + hist[bin] >= (unsigned)HTHR) break;
      cum += hist[bin];
    }
    sB = bin;
  }
  __syncthreads();
  const unsigned B = (unsigned)sB;
#pragma unroll
  for (int i = 0; i < 2; ++i) {
    if ((key2[i] >> 20) > B) {
      unsigned pos = atomicAdd(&sCntHi, 1u);
      s_cand[pos] = t + i * 1024;
    }
  }
  __syncthreads();
  const unsigned hi = sCntHi;
#pragma unroll
  for (int i = 0; i < 2; ++i) {
    if ((key2[i] >> 20) == B) {
      unsigned pos = atomicAdd(&sCntB, 1u);
      if (hi + pos < (unsigned)MCAP) s_cand[hi + pos] = t + i * 1024;
    }
  }
  __syncthreads();
  if (t == 0) {
    unsigned n = sCntHi + sCntB;
    sN = (n < (unsigned)MCAP) ? n : (unsigned)MCAP;
  }
  __syncthreads();
  const int n = (int)sN;

  // --- phase B: exact fp32 rescore (FMA ordering identical to old k_rescore) ---
  const int hg = t & 63;   // lane = h-quad index
  const int rg = t >> 6;   // wave index, 16 groups
  const float4* Wp = (const float4*)W1;
  const float4 wvq = ((const float4*)w2)[hg];
  const float4 Tvq = ((const float4*)(T + (size_t)b * NH))[hg];
  const float b2v = b2[0];
#pragma unroll 1
  for (int pass = 0; pass < MCAP / 16; ++pass) {
    const int slot = pass * 16 + rg;
    if (slot < n) {
      const int l = s_cand[slot];
      const float* srow = seq + ((size_t)b * NL + l) * ND;
      float a0 = 0.f, a1 = 0.f, a2 = 0.f, a3 = 0.f;
      for (int d0 = 0; d0 < ND; d0 += 4) {
        float4 wq[4];
#pragma unroll
        for (int j = 0; j < 4; ++j) wq[j] = Wp[(size_t)(d0 + j) * (NH / 4) + hg];
        const float4 s = *(const float4*)(srow + d0);
        const float sv[4] = {s.x, s.y, s.z, s.w};
#pragma unroll
        for (int j = 0; j < 4; ++j) {
          a0 = fmaf(sv[j], wq[j].x, a0);
          a1 = fmaf(sv[j], wq[j].y, a1);
          a2 = fmaf(sv[j], wq[j].z, a2);
          a3 = fmaf(sv[j], wq[j].w, a3);
        }
      }
      const float4 Pv = ((const float4*)(P + (size_t)l * NH))[hg];
      float z, p = 0.0f;
      z = a0 + Pv.x + Tvq.x; p = fmaf(fmaxf(z, 0.0f), wvq.x, p);
      z = a1 + Pv.y + Tvq.y; p = fmaf(fmaxf(z, 0.0f), wvq.y, p);
      z = a2 + Pv.z + Tvq.z; p = fmaf(fmaxf(z, 0.0f), wvq.z, p);
      z = a3 + Pv.w + Tvq.w; p = fmaf(fmaxf(z, 0.0f), wvq.w, p);
#pragma unroll
      for (int off = 32; off >= 1; off >>= 1) p += __shfl_xor(p, off);
      if (hg == 0) {
        float sc = p + b2v;
        if (mask[(size_t)b * NL + l] == 0) sc = MASK_FILL_F;
        s_cs[slot] = sc;
      }
    }
  }
  __syncthreads();

  // --- phase C: rank-based exact top-64, index-sort, softmax ---
  for (int s = t; s < MCAP; s += 1024) {
    unsigned long long kk = 0ull;
    if (s < n) {
      unsigned u = __float_as_uint(s_cs[s]);
      u = (u & 0x80000000u) ? ~u : (u | 0x80000000u);
      const int l = s_cand[s];
      kk = ((unsigned long long)u << 11) | (unsigned long long)(NL - 1 - l);
    }
    s_key[s] = kk;
  }
  __syncthreads();
  for (int s = t; s < MCAP; s += 1024) {
    if (s < n) {
      const unsigned long long mk = s_key[s];
      int rank = 0;
      for (int j = 0; j < n; ++j) rank += (s_key[j] > mk) ? 1 : 0;
      if (rank < NK) {
        sel_l[rank] = (NL - 1) - (int)(mk & 0x7FFull);
        sel_v[rank] = s_cs[s];
      }
    }
  }
  __syncthreads();
  if (t < NK) {
    const int myl = sel_l[t];
    int pos = 0;
#pragma unroll 8
    for (int j = 0; j < NK; ++j) pos += (sel_l[j] < myl) ? 1 : 0;
    srt_l[pos] = myl;
    srt_v[pos] = sel_v[t];
  }
  __syncthreads();
  if (t < 64) {
    const float sc = srt_v[t];
    float m = sc;
#pragma unroll
    for (int off = 32; off >= 1; off >>= 1) m = fmaxf(m, __shfl_xor(m, off));
    const float e = expf(sc - m);
    float s = e;
#pragma unroll
    for (int off = 32; off >= 1; off >>= 1) s += __shfl_xor(s, off);
    attn[(size_t)b * NK + t] = e / s;
    idx_sorted[(size_t)b * NK + t] = srt_l[t];
  }
}

// ---------- fused encoder: enc1 + enc2 + attn pool + layernorm ----------
// one block per batch, 1024 threads; h1 lives in LDS (never touches HBM).
__global__ __launch_bounds__(1024) void k_encode(
    const float* __restrict__ seq, const float* __restrict__ pos,
    const int* __restrict__ idx_sorted, const float* __restrict__ attn_g,
    const float* __restrict__ We1, const float* __restrict__ be1,
    const float* __restrict__ We2, const float* __restrict__ be2,
    const float* __restrict__ gamma, const float* __restrict__ beta,
    float* __restrict__ out) {
  const int b = blockIdx.x, t = threadIdx.x;
  __shared__ float s_in[NK * 256];  // 64 KB: [k][seq|pos]
  __shared__ float s_h1[NK * NH];   // 64 KB
  __shared__ float red[8 * NO];     // 4 KB
  __shared__ float rr[4];
  __shared__ int s_idx[NK];
  __shared__ float s_at[NK];

  if (t < NK) {
    s_idx[t] = idx_sorted[(size_t)b * NK + t];
    s_at[t] = attn_g[(size_t)b * NK + t];
  }
  __syncthreads();
  {  // gather [seq|pos] rows: 16 threads per row
    const int k = t >> 4, q = t & 15;
    const int idx = s_idx[k];
    const float4* sr = (const float4*)(seq + ((size_t)b * NL + idx) * ND);
    const float4* pr = (const float4*)(pos + (size_t)idx * ND);
    float4* d1 = (float4*)&s_in[k * 256];
    float4* d2 = (float4*)&s_in[k * 256 + ND];
#pragma unroll
    for (int i = 0; i < 2; ++i) {
      d1[q + i * 16] = sr[q + i * 16];
      d2[q + i * 16] = pr[q + i * 16];
    }
  }
  __syncthreads();

  {  // enc1: h = t&255, 4 kg groups x 16 rows
    const int h = t & 255, kg = t >> 8;
    float acc[16];
#pragma unroll
    for (int r = 0; r < 16; ++r) acc[r] = 0.0f;
    for (int d = 0; d < 2 * ND; ++d) {
      const float w = We1[(size_t)d * NH + h];
#pragma unroll
      for (int r = 0; r < 16; ++r)
        acc[r] = fmaf(s_in[(kg * 16 + r) * 256 + d], w, acc[r]);
    }
    const float bv = be1[h];
#pragma unroll
    for (int r = 0; r < 16; ++r)
      s_h1[(kg * 16 + r) * NH + h] = fmaxf(acc[r] + bv, 0.0f);
  }
  __syncthreads();

  {  // enc2 + attn pool partials: o = t&127, 8 kg groups x 8 rows
    const int o = t & 127, kg = t >> 7;
    float acc[8];
#pragma unroll
    for (int r = 0; r < 8; ++r) acc[r] = 0.0f;
    for (int d = 0; d < NH; ++d) {
      const float w = We2[(size_t)d * NO + o];
#pragma unroll
      for (int r = 0; r < 8; ++r)
        acc[r] = fmaf(s_h1[(kg * 8 + r) * NH + d], w, acc[r]);
    }
    const float bv = be2[o];
    float part = 0.0f;
#pragma unroll
    for (int r = 0; r < 8; ++r)
      part = fmaf(s_at[kg * 8 + r], acc[r] + bv, part);
    red[kg * NO + o] = part;
  }
  __syncthreads();

  float pooled = 0.0f;
  if (t < NO) {
#pragma unroll
    for (int g = 0; g < 8; ++g) pooled += red[g * NO + t];
  }
  float s1 = (t < NO) ? pooled : 0.0f;
  float s2 = (t < NO) ? pooled * pooled : 0.0f;
#pragma unroll
  for (int off = 32; off >= 1; off >>= 1) {
    s1 += __shfl_xor(s1, off);
    s2 += __shfl_xor(s2, off);
  }
  if (t < NO && (t & 63) == 0) {
    rr[(t >> 6) * 2] = s1;
    rr[(t >> 6) * 2 + 1] = s2;
  }
  __syncthreads();
  if (t < NO) {
    const float S1 = rr[0] + rr[2];
    const float S2 = rr[1] + rr[3];
    const float mu = S1 / NO;
    const float var = S2 / NO - mu * mu;
    const float rs = rsqrtf(var + LN_EPS_F);
    out[(size_t)b * NO + t] = (pooled - mu) * rs * gamma[t] + beta[t];
  }
}

extern "C" void kernel_launch(void* const* d_in, const int* in_sizes, int n_in,
                              void* d_out, int out_size, void* d_ws, size_t ws_size,
                              hipStream_t stream) {
  (void)in_sizes; (void)n_in; (void)out_size; (void)ws_size;
  const float* seq = (const float*)d_in[0];
  const int* mask = (const int*)d_in[1];
  const float* tgt = (const float*)d_in[2];
  const float* pos = (const float*)d_in[3];
  const float* W1 = (const float*)d_in[4];
  const float* b1 = (const float*)d_in[5];
  const float* w2 = (const float*)d_in[6];
  const float* b2 = (const float*)d_in[7];
  const float* We1 = (const float*)d_in[8];
  const float* be1 = (const float*)d_in[9];
  const float* We2 = (const float*)d_in[10];
  const float* be2 = (const float*)d_in[11];
  const float* gam = (const float*)d_in[12];
  const float* bet = (const float*)d_in[13];
  float* out = (float*)d_out;

  float* P = (float*)d_ws;                            // NL*NH
  float* T = P + (size_t)NL * NH;                     // NB*NH
  float* scores = T + (size_t)NB * NH;                // NB*NL
  float* attn = scores + (size_t)NB * NL;             // NB*NK
  int* idxs = (int*)(attn + (size_t)NB * NK);         // NB*NK
  unsigned short* w1aT = (unsigned short*)(idxs + (size_t)NB * NK);  // NH*ND bf16

  k_prep<<<ND + NL + NB, 256, 0, stream>>>(W1, pos, tgt, b1, w1aT, P, T);
  k_scores_mfma<<<dim3(NL / 128, NB / BLOOP), 512, 0, stream>>>(
      seq, mask, w1aT, w2, b2, b1, T, scores);
  k_select3<<<NB, 1024, 0, stream>>>(scores, seq, mask, W1, w2, b2, P, T,
                                     idxs, attn);
  k_encode<<<NB, 1024, 0, stream>>>(seq, pos, idxs, attn, We1, be1, We2, be2,
                                    gam, bet, out);
}

// Round 11
// 183.779 us; speedup vs baseline: 3.6209x; 3.6209x over previous
//
#include <hip/hip_runtime.h>
#include <hip/hip_bf16.h>

namespace {
constexpr int NB = 128;   // batch
constexpr int NL = 2048;  // seq len
constexpr int ND = 128;   // emb dim
constexpr int NH = 256;   // hidden
constexpr int NO = 128;   // encoder out dim
constexpr int NK = 64;    // top-k
constexpr int MCAP = 192; // candidate cap per batch
constexpr int HTHR = 96;  // histogram cumulative threshold
constexpr int BLOOP = 8;  // batches per score block
constexpr float MASK_FILL_F = -1e9f;
constexpr float LN_EPS_F = 1e-5f;
}

typedef __attribute__((ext_vector_type(8))) short bf16x8;
typedef __attribute__((ext_vector_type(4))) float f32x4;

__device__ __forceinline__ unsigned short bf16rne(float x) {
  unsigned u = __float_as_uint(x);
  return (unsigned short)((u + 0x7FFFu + ((u >> 16) & 1u)) >> 16);
}

// ---------- fused prep: W1 seq-slab -> bf16T | P[l,h] | T[b,h] ----------
// (R8 lesson: single-row contrib blocks, 2304 total, 8 blocks/CU TLP)
__global__ __launch_bounds__(256) void k_prep(
    const float* __restrict__ W1, const float* __restrict__ pos,
    const float* __restrict__ tgt, const float* __restrict__ b1,
    unsigned short* __restrict__ W1aT, float* __restrict__ P,
    float* __restrict__ T) {
  const int blk = blockIdx.x, t = threadIdx.x;
  if (blk < ND) {  // W1aT[h][d]: d = blk (0..127), h = t (0..255)
    W1aT[(size_t)t * ND + blk] = bf16rne(W1[(size_t)blk * NH + t]);
    return;
  }
  int r, w_off, add_bias;
  const float* src;
  float* out;
  if (blk < ND + NL) {
    r = blk - ND; src = pos; out = P; w_off = ND; add_bias = 1;
  } else {
    r = blk - (ND + NL); src = tgt; out = T; w_off = 2 * ND; add_bias = 0;
  }
  __shared__ float row[ND];
  if (t < ND) row[t] = src[(size_t)r * ND + t];
  __syncthreads();
  float acc = add_bias ? b1[t] : 0.0f;
#pragma unroll 8
  for (int d = 0; d < ND; ++d)
    acc = fmaf(row[d], W1[(size_t)(w_off + d) * NH + t], acc);
  out[(size_t)r * NH + t] = acc;
}

// ---------- approximate scores (identical to R9 / validated config) ----------
__global__ __launch_bounds__(512, 2) void k_scores_mfma(
    const float* __restrict__ seq, const int* __restrict__ mask,
    const unsigned short* __restrict__ W1aT, const float* __restrict__ w2,
    const float* __restrict__ b2, const float* __restrict__ b1,
    const float* __restrict__ T, float* __restrict__ scores) {
  const int l0 = blockIdx.x * 128;
  const int b0 = blockIdx.y * BLOOP;
  const int t = threadIdx.x;
  const int lane = t & 63;
  const int w = t >> 6;      // 0..7
  const int wh = w & 3;      // h-block
  const int wl = w >> 2;     // l-block
  const int lh = lane & 15;
  const int kq = lane >> 4;  // 0..3

  __shared__ unsigned short sSeq[2][128 * 128];  // 2 x 32 KB dbuf, swizzled
  __shared__ float sRed[4][128];

  bf16x8 a[4][4];
#pragma unroll
  for (int ks = 0; ks < 4; ++ks)
#pragma unroll
    for (int mt = 0; mt < 4; ++mt)
      a[ks][mt] = *(const bf16x8*)(
          W1aT + (size_t)(wh * 64 + mt * 16 + lh) * ND + ks * 32 + kq * 8);

  float4 wv[4], b1v[4];
#pragma unroll
  for (int mt = 0; mt < 4; ++mt) {
    wv[mt] = *(const float4*)(w2 + wh * 64 + mt * 16 + kq * 4);
    b1v[mt] = *(const float4*)(b1 + wh * 64 + mt * 16 + kq * 4);
  }
  const float b2v = b2[0];

  ushort4 pf[8];
  auto prefetch = [&](int bb) {
    const float4* g = (const float4*)(seq + ((size_t)bb * NL + l0) * ND);
#pragma unroll
    for (int i = 0; i < 8; ++i) {
      const float4 f = g[t + i * 512];
      pf[i].x = bf16rne(f.x); pf[i].y = bf16rne(f.y);
      pf[i].z = bf16rne(f.z); pf[i].w = bf16rne(f.w);
    }
  };
  auto commit = [&](unsigned short* dst) {
#pragma unroll
    for (int i = 0; i < 8; ++i) {
      const int v = t + i * 512;
      const int row = v >> 5;
      const int c8 = (v & 31) * 8;
      const int off = (row << 8) + (c8 ^ ((row & 15) << 4));
      *(ushort4*)((char*)dst + off) = pf[i];
    }
  };

  prefetch(b0);
  commit((unsigned short*)sSeq[0]);
  __syncthreads();

#pragma unroll 1
  for (int j = 0; j < BLOOP; ++j) {
    const int b = b0 + j;
    unsigned short* cSeq = (unsigned short*)sSeq[j & 1];
    unsigned short* nSeq = (unsigned short*)sSeq[(j & 1) ^ 1];

    if (j + 1 < BLOOP) prefetch(b + 1);

    float4 Tv[4];
#pragma unroll
    for (int mt = 0; mt < 4; ++mt)
      Tv[mt] = *(const float4*)(T + (size_t)b * NH + wh * 64 + mt * 16 + kq * 4);

    f32x4 acc[4][4];
#pragma unroll
    for (int mt = 0; mt < 4; ++mt)
#pragma unroll
      for (int nt = 0; nt < 4; ++nt) acc[mt][nt] = (f32x4){0.f, 0.f, 0.f, 0.f};

#pragma unroll
    for (int ks = 0; ks < 4; ++ks) {
      bf16x8 Bf[4];
#pragma unroll
      for (int nt = 0; nt < 4; ++nt) {
        const int row = wl * 64 + nt * 16 + lh;
        const int off = (row << 8) + (((ks << 6) + (kq << 4)) ^ ((row & 15) << 4));
        Bf[nt] = *(const bf16x8*)((const char*)cSeq + off);
      }
#pragma unroll
      for (int mt = 0; mt < 4; ++mt)
#pragma unroll
        for (int nt = 0; nt < 4; ++nt)
          acc[mt][nt] = __builtin_amdgcn_mfma_f32_16x16x32_bf16(
              a[ks][mt], Bf[nt], acc[mt][nt], 0, 0, 0);
    }
    __syncthreads();
    if (j + 1 < BLOOP) commit(nSeq);

    float p[4] = {0.f, 0.f, 0.f, 0.f};
#pragma unroll
    for (int mt = 0; mt < 4; ++mt) {
#pragma unroll
      for (int nt = 0; nt < 4; ++nt) {
        float z;
        z = acc[mt][nt][0] + Tv[mt].x + b1v[mt].x; p[nt] = fmaf(fmaxf(z, 0.f), wv[mt].x, p[nt]);
        z = acc[mt][nt][1] + Tv[mt].y + b1v[mt].y; p[nt] = fmaf(fmaxf(z, 0.f), wv[mt].y, p[nt]);
        z = acc[mt][nt][2] + Tv[mt].z + b1v[mt].z; p[nt] = fmaf(fmaxf(z, 0.f), wv[mt].z, p[nt]);
        z = acc[mt][nt][3] + Tv[mt].w + b1v[mt].w; p[nt] = fmaf(fmaxf(z, 0.f), wv[mt].w, p[nt]);
      }
    }
#pragma unroll
    for (int nt = 0; nt < 4; ++nt) {
      float v = p[nt];
      v += __shfl_xor(v, 16);
      v += __shfl_xor(v, 32);
      if (lane < 16) sRed[wh][wl * 64 + nt * 16 + lane] = v;
    }
    __syncthreads();
    if (t < 128) {
      const int l = l0 + t;
      float sc = sRed[0][t] + sRed[1][t] + sRed[2][t] + sRed[3][t] + b2v;
      if (mask[(size_t)b * NL + l] == 0) sc = MASK_FILL_F;
      scores[(size_t)b * NL + l] = sc;
    }
  }
}

// ---------- fused: histogram topM + LDS-staged exact rescore + select ----------
// one block per batch, 1024 threads (16 waves).
// Phase B uses the R9 k_rescore structure: seq rows staged in LDS, 8 rows per
// thread so each W1 wq[4] load amortizes over 8 rows (R10's per-wave-per-row
// global reads caused 288 MB HBM fetch / 554us).
__global__ __launch_bounds__(1024, 4) void k_select3(
    const float* __restrict__ scores, const float* __restrict__ seq,
    const int* __restrict__ mask, const float* __restrict__ W1,
    const float* __restrict__ w2, const float* __restrict__ b2,
    const float* __restrict__ P, const float* __restrict__ T,
    int* __restrict__ idx_sorted, float* __restrict__ attn) {
  const int b = blockIdx.x, t = threadIdx.x;
  __shared__ float s_stage[128 * ND];   // 64 KB; phase A aliases hist here
  unsigned* hist = (unsigned*)s_stage;  // 4096 uints = 16 KB
  __shared__ unsigned chunk[256];
  __shared__ int sB;
  __shared__ unsigned sCntHi, sCntB, sN;
  __shared__ int s_cand[MCAP];
  __shared__ float s_cs[MCAP];
  __shared__ unsigned long long s_key[MCAP];
  __shared__ int sel_l[NK];
  __shared__ float sel_v[NK];
  __shared__ int srt_l[NK];
  __shared__ float srt_v[NK];

  // --- phase A: histogram over monotone keys ---
  for (int i = t; i < 4096; i += 1024) hist[i] = 0;
  if (t == 0) { sCntHi = 0; sCntB = 0; }
  __syncthreads();
  unsigned key2[2];
#pragma unroll
  for (int i = 0; i < 2; ++i) {
    unsigned u = __float_as_uint(scores[(size_t)b * NL + t + i * 1024]);
    u = (u & 0x80000000u) ? ~u : (u | 0x80000000u);
    key2[i] = u;
    atomicAdd(&hist[u >> 20], 1u);
  }
  __syncthreads();
  if (t < 256) {
    unsigned s = 0;
#pragma unroll 4
    for (int j = 0; j < 16; ++j) s += hist[t * 16 + j];
    chunk[t] = s;
  }
  __syncthreads();
  if (t == 0) {
    unsigned cum = 0;
    int c = 255;
    for (; c > 0; --c) {
      if (cum + chunk[c] >= (unsigned)HTHR) break;
      cum += chunk[c];
    }
    int bin = c * 16 + 15;
    for (; bin > c * 16; --bin) {
      if (cum + hist[bin] >= (unsigned)HTHR) break;
      cum += hist[bin];
    }
    sB = bin;
  }
  __syncthreads();
  const unsigned B = (unsigned)sB;
#pragma unroll
  for (int i = 0; i < 2; ++i) {
    if ((key2[i] >> 20) > B) {
      unsigned pos = atomicAdd(&sCntHi, 1u);
      s_cand[pos] = t + i * 1024;
    }
  }
  __syncthreads();
  const unsigned hi = sCntHi;
#pragma unroll
  for (int i = 0; i < 2; ++i) {
    if ((key2[i] >> 20) == B) {
      unsigned pos = atomicAdd(&sCntB, 1u);
      if (hi + pos < (unsigned)MCAP) s_cand[hi + pos] = t + i * 1024;
    }
  }
  __syncthreads();
  if (t == 0) {
    unsigned n = sCntHi + sCntB;
    sN = (n < (unsigned)MCAP) ? n : (unsigned)MCAP;
  }
  __syncthreads();
  const int n = (int)sN;  // n >= HTHR = 96 always

  // --- phase B: exact fp32 rescore, 128 rows/pass staged in LDS ---
  const int hg = t & 63;   // h-quad index
  const int rg = t >> 6;   // 16 row-groups x 8 rows
  const float4* Wp = (const float4*)W1;
  const float4 wvq = ((const float4*)w2)[hg];
  const float4 Tvq = ((const float4*)(T + (size_t)b * NH))[hg];
  const float b2v = b2[0];
#pragma unroll 1
  for (int pass = 0; pass < 2; ++pass) {
    const int base = pass * 128;
    if (base >= n) break;
    __syncthreads();  // hist/prev-stage dead before overwrite
#pragma unroll
    for (int i = 0; i < 4; ++i) {
      const int v = t + i * 1024;       // 4096 float4 = 128 rows x 32
      const int r = v >> 5, c = v & 31;
      const int slot = base + r;
      const int l = (slot < n) ? s_cand[slot] : 0;
      ((float4*)s_stage)[r * 32 + c] =
          ((const float4*)(seq + ((size_t)b * NL + l) * ND))[c];
    }
    __syncthreads();

    float acc[8][4];
#pragma unroll
    for (int r = 0; r < 8; ++r)
#pragma unroll
      for (int j = 0; j < 4; ++j) acc[r][j] = 0.0f;

    for (int d0 = 0; d0 < ND; d0 += 4) {
      float4 wq[4];
#pragma unroll
      for (int j = 0; j < 4; ++j) wq[j] = Wp[(size_t)(d0 + j) * (NH / 4) + hg];
#pragma unroll
      for (int r = 0; r < 8; ++r) {
        const float4 s = *(const float4*)&s_stage[(rg * 8 + r) * ND + d0];
        const float sv[4] = {s.x, s.y, s.z, s.w};
#pragma unroll
        for (int j = 0; j < 4; ++j) {
          acc[r][0] = fmaf(sv[j], wq[j].x, acc[r][0]);
          acc[r][1] = fmaf(sv[j], wq[j].y, acc[r][1]);
          acc[r][2] = fmaf(sv[j], wq[j].z, acc[r][2]);
          acc[r][3] = fmaf(sv[j], wq[j].w, acc[r][3]);
        }
      }
    }

#pragma unroll
    for (int r = 0; r < 8; ++r) {
      const int slot = base + rg * 8 + r;
      const int l = (slot < n) ? s_cand[slot] : 0;
      const float4 Pv = ((const float4*)(P + (size_t)l * NH))[hg];
      float z, p = 0.0f;
      z = acc[r][0] + Pv.x + Tvq.x; p = fmaf(fmaxf(z, 0.0f), wvq.x, p);
      z = acc[r][1] + Pv.y + Tvq.y; p = fmaf(fmaxf(z, 0.0f), wvq.y, p);
      z = acc[r][2] + Pv.z + Tvq.z; p = fmaf(fmaxf(z, 0.0f), wvq.z, p);
      z = acc[r][3] + Pv.w + Tvq.w; p = fmaf(fmaxf(z, 0.0f), wvq.w, p);
#pragma unroll
      for (int off = 32; off >= 1; off >>= 1) p += __shfl_xor(p, off);
      if (hg == 0 && slot < n) {
        float sc = p + b2v;
        if (mask[(size_t)b * NL + l] == 0) sc = MASK_FILL_F;
        s_cs[slot] = sc;
      }
    }
  }
  __syncthreads();

  // --- phase C: rank-based exact top-64, index-sort, softmax ---
  for (int s = t; s < MCAP; s += 1024) {
    unsigned long long kk = 0ull;
    if (s < n) {
      unsigned u = __float_as_uint(s_cs[s]);
      u = (u & 0x80000000u) ? ~u : (u | 0x80000000u);
      const int l = s_cand[s];
      kk = ((unsigned long long)u << 11) | (unsigned long long)(NL - 1 - l);
    }
    s_key[s] = kk;
  }
  __syncthreads();
  for (int s = t; s < MCAP; s += 1024) {
    if (s < n) {
      const unsigned long long mk = s_key[s];
      int rank = 0;
      for (int j = 0; j < n; ++j) rank += (s_key[j] > mk) ? 1 : 0;
      if (rank < NK) {
        sel_l[rank] = (NL - 1) - (int)(mk & 0x7FFull);
        sel_v[rank] = s_cs[s];
      }
    }
  }
  __syncthreads();
  if (t < NK) {
    const int myl = sel_l[t];
    int pos = 0;
#pragma unroll 8
    for (int j = 0; j < NK; ++j) pos += (sel_l[j] < myl) ? 1 : 0;
    srt_l[pos] = myl;
    srt_v[pos] = sel_v[t];
  }
  __syncthreads();
  if (t < 64) {
    const float sc = srt_v[t];
    float m = sc;
#pragma unroll
    for (int off = 32; off >= 1; off >>= 1) m = fmaxf(m, __shfl_xor(m, off));
    const float e = expf(sc - m);
    float s = e;
#pragma unroll
    for (int off = 32; off >= 1; off >>= 1) s += __shfl_xor(s, off);
    attn[(size_t)b * NK + t] = e / s;
    idx_sorted[(size_t)b * NK + t] = srt_l[t];
  }
}

// ---------- fused encoder: enc1 + enc2 + attn pool + layernorm ----------
__global__ __launch_bounds__(1024) void k_encode(
    const float* __restrict__ seq, const float* __restrict__ pos,
    const int* __restrict__ idx_sorted, const float* __restrict__ attn_g,
    const float* __restrict__ We1, const float* __restrict__ be1,
    const float* __restrict__ We2, const float* __restrict__ be2,
    const float* __restrict__ gamma, const float* __restrict__ beta,
    float* __restrict__ out) {
  const int b = blockIdx.x, t = threadIdx.x;
  __shared__ float s_in[NK * 256];  // 64 KB: [k][seq|pos]
  __shared__ float s_h1[NK * NH];   // 64 KB
  __shared__ float red[8 * NO];     // 4 KB
  __shared__ float rr[4];
  __shared__ int s_idx[NK];
  __shared__ float s_at[NK];

  if (t < NK) {
    s_idx[t] = idx_sorted[(size_t)b * NK + t];
    s_at[t] = attn_g[(size_t)b * NK + t];
  }
  __syncthreads();
  {
    const int k = t >> 4, q = t & 15;
    const int idx = s_idx[k];
    const float4* sr = (const float4*)(seq + ((size_t)b * NL + idx) * ND);
    const float4* pr = (const float4*)(pos + (size_t)idx * ND);
    float4* d1 = (float4*)&s_in[k * 256];
    float4* d2 = (float4*)&s_in[k * 256 + ND];
#pragma unroll
    for (int i = 0; i < 2; ++i) {
      d1[q + i * 16] = sr[q + i * 16];
      d2[q + i * 16] = pr[q + i * 16];
    }
  }
  __syncthreads();

  {  // enc1: h = t&255, 4 kg groups x 16 rows
    const int h = t & 255, kg = t >> 8;
    float acc[16];
#pragma unroll
    for (int r = 0; r < 16; ++r) acc[r] = 0.0f;
    for (int d = 0; d < 2 * ND; ++d) {
      const float w = We1[(size_t)d * NH + h];
#pragma unroll
      for (int r = 0; r < 16; ++r)
        acc[r] = fmaf(s_in[(kg * 16 + r) * 256 + d], w, acc[r]);
    }
    const float bv = be1[h];
#pragma unroll
    for (int r = 0; r < 16; ++r)
      s_h1[(kg * 16 + r) * NH + h] = fmaxf(acc[r] + bv, 0.0f);
  }
  __syncthreads();

  {  // enc2 + attn pool partials: o = t&127, 8 kg groups x 8 rows
    const int o = t & 127, kg = t >> 7;
    float acc[8];
#pragma unroll
    for (int r = 0; r < 8; ++r) acc[r] = 0.0f;
    for (int d = 0; d < NH; ++d) {
      const float w = We2[(size_t)d * NO + o];
#pragma unroll
      for (int r = 0; r < 8; ++r)
        acc[r] = fmaf(s_h1[(kg * 8 + r) * NH + d], w, acc[r]);
    }
    const float bv = be2[o];
    float part = 0.0f;
#pragma unroll
    for (int r = 0; r < 8; ++r)
      part = fmaf(s_at[kg * 8 + r], acc[r] + bv, part);
    red[kg * NO + o] = part;
  }
  __syncthreads();

  float pooled = 0.0f;
  if (t < NO) {
#pragma unroll
    for (int g = 0; g < 8; ++g) pooled += red[g * NO + t];
  }
  float s1 = (t < NO) ? pooled : 0.0f;
  float s2 = (t < NO) ? pooled * pooled : 0.0f;
#pragma unroll
  for (int off = 32; off >= 1; off >>= 1) {
    s1 += __shfl_xor(s1, off);
    s2 += __shfl_xor(s2, off);
  }
  if (t < NO && (t & 63) == 0) {
    rr[(t >> 6) * 2] = s1;
    rr[(t >> 6) * 2 + 1] = s2;
  }
  __syncthreads();
  if (t < NO) {
    const float S1 = rr[0] + rr[2];
    const float S2 = rr[1] + rr[3];
    const float mu = S1 / NO;
    const float var = S2 / NO - mu * mu;
    const float rs = rsqrtf(var + LN_EPS_F);
    out[(size_t)b * NO + t] = (pooled - mu) * rs * gamma[t] + beta[t];
  }
}

extern "C" void kernel_launch(void* const* d_in, const int* in_sizes, int n_in,
                              void* d_out, int out_size, void* d_ws, size_t ws_size,
                              hipStream_t stream) {
  (void)in_sizes; (void)n_in; (void)out_size; (void)ws_size;
  const float* seq = (const float*)d_in[0];
  const int* mask = (const int*)d_in[1];
  const float* tgt = (const float*)d_in[2];
  const float* pos = (const float*)d_in[3];
  const float* W1 = (const float*)d_in[4];
  const float* b1 = (const float*)d_in[5];
  const float* w2 = (const float*)d_in[6];
  const float* b2 = (const float*)d_in[7];
  const float* We1 = (const float*)d_in[8];
  const float* be1 = (const float*)d_in[9];
  const float* We2 = (const float*)d_in[10];
  const float* be2 = (const float*)d_in[11];
  const float* gam = (const float*)d_in[12];
  const float* bet = (const float*)d_in[13];
  float* out = (float*)d_out;

  float* P = (float*)d_ws;                            // NL*NH
  float* T = P + (size_t)NL * NH;                     // NB*NH
  float* scores = T + (size_t)NB * NH;                // NB*NL
  float* attn = scores + (size_t)NB * NL;             // NB*NK
  int* idxs = (int*)(attn + (size_t)NB * NK);         // NB*NK
  unsigned short* w1aT = (unsigned short*)(idxs + (size_t)NB * NK);  // NH*ND bf16

  k_prep<<<ND + NL + NB, 256, 0, stream>>>(W1, pos, tgt, b1, w1aT, P, T);
  k_scores_mfma<<<dim3(NL / 128, NB / BLOOP), 512, 0, stream>>>(
      seq, mask, w1aT, w2, b2, b1, T, scores);
  k_select3<<<NB, 1024, 0, stream>>>(scores, seq, mask, W1, w2, b2, P, T,
                                     idxs, attn);
  k_encode<<<NB, 1024, 0, stream>>>(seq, pos, idxs, attn, We1, be1, We2, be2,
                                    gam, bet, out);
}

// Round 12
// 142.113 us; speedup vs baseline: 4.6825x; 1.2932x over previous
//
#include <hip/hip_runtime.h>
#include <hip/hip_bf16.h>

namespace {
constexpr int NB = 128;   // batch
constexpr int NL = 2048;  // seq len
constexpr int ND = 128;   // emb dim
constexpr int NH = 256;   // hidden
constexpr int NO = 128;   // encoder out dim
constexpr int NK = 64;    // top-k
constexpr int MCAP = 192; // candidate cap per batch
constexpr int HTHR = 96;  // histogram cumulative threshold
constexpr int BLOOP = 8;  // batches per score block
constexpr float MASK_FILL_F = -1e9f;
constexpr float LN_EPS_F = 1e-5f;
}

typedef __attribute__((ext_vector_type(8))) short bf16x8;
typedef __attribute__((ext_vector_type(4))) float f32x4;

__device__ __forceinline__ unsigned short bf16rne(float x) {
  unsigned u = __float_as_uint(x);
  return (unsigned short)((u + 0x7FFFu + ((u >> 16) & 1u)) >> 16);
}

// ---------- fused prep: W1aT | P | T | We1T | We2T ----------
// grid: [0,ND) w1aT; [ND,ND+NL) P; +NB T; +256 we1T; +256 we2T
__global__ __launch_bounds__(256) void k_prep(
    const float* __restrict__ W1, const float* __restrict__ pos,
    const float* __restrict__ tgt, const float* __restrict__ b1,
    const float* __restrict__ We1, const float* __restrict__ We2,
    unsigned short* __restrict__ W1aT, float* __restrict__ P,
    float* __restrict__ T, unsigned short* __restrict__ We1T,
    unsigned short* __restrict__ We2T) {
  const int blk = blockIdx.x, t = threadIdx.x;
  if (blk < ND) {  // W1aT[h][d]
    W1aT[(size_t)t * ND + blk] = bf16rne(W1[(size_t)blk * NH + t]);
    return;
  }
  if (blk >= ND + NL + NB) {
    const int b2 = blk - (ND + NL + NB);
    if (b2 < 256) {  // We1T[h][d]: d = b2, h = t
      We1T[(size_t)t * 256 + b2] = bf16rne(We1[(size_t)b2 * NH + t]);
    } else {         // We2T[o][d]: d = b2-256, o = t (<128)
      const int d = b2 - 256;
      if (t < NO) We2T[(size_t)t * 256 + d] = bf16rne(We2[(size_t)d * NO + t]);
    }
    return;
  }
  int r, w_off, add_bias;
  const float* src;
  float* out;
  if (blk < ND + NL) {
    r = blk - ND; src = pos; out = P; w_off = ND; add_bias = 1;
  } else {
    r = blk - (ND + NL); src = tgt; out = T; w_off = 2 * ND; add_bias = 0;
  }
  __shared__ float row[ND];
  if (t < ND) row[t] = src[(size_t)r * ND + t];
  __syncthreads();
  float acc = add_bias ? b1[t] : 0.0f;
#pragma unroll 8
  for (int d = 0; d < ND; ++d)
    acc = fmaf(row[d], W1[(size_t)(w_off + d) * NH + t], acc);
  out[(size_t)r * NH + t] = acc;
}

// ---------- approximate scores (identical to validated config) ----------
__global__ __launch_bounds__(512, 2) void k_scores_mfma(
    const float* __restrict__ seq, const int* __restrict__ mask,
    const unsigned short* __restrict__ W1aT, const float* __restrict__ w2,
    const float* __restrict__ b2, const float* __restrict__ b1,
    const float* __restrict__ T, float* __restrict__ scores) {
  const int l0 = blockIdx.x * 128;
  const int b0 = blockIdx.y * BLOOP;
  const int t = threadIdx.x;
  const int lane = t & 63;
  const int w = t >> 6;
  const int wh = w & 3;
  const int wl = w >> 2;
  const int lh = lane & 15;
  const int kq = lane >> 4;

  __shared__ unsigned short sSeq[2][128 * 128];
  __shared__ float sRed[4][128];

  bf16x8 a[4][4];
#pragma unroll
  for (int ks = 0; ks < 4; ++ks)
#pragma unroll
    for (int mt = 0; mt < 4; ++mt)
      a[ks][mt] = *(const bf16x8*)(
          W1aT + (size_t)(wh * 64 + mt * 16 + lh) * ND + ks * 32 + kq * 8);

  float4 wv[4], b1v[4];
#pragma unroll
  for (int mt = 0; mt < 4; ++mt) {
    wv[mt] = *(const float4*)(w2 + wh * 64 + mt * 16 + kq * 4);
    b1v[mt] = *(const float4*)(b1 + wh * 64 + mt * 16 + kq * 4);
  }
  const float b2v = b2[0];

  ushort4 pf[8];
  auto prefetch = [&](int bb) {
    const float4* g = (const float4*)(seq + ((size_t)bb * NL + l0) * ND);
#pragma unroll
    for (int i = 0; i < 8; ++i) {
      const float4 f = g[t + i * 512];
      pf[i].x = bf16rne(f.x); pf[i].y = bf16rne(f.y);
      pf[i].z = bf16rne(f.z); pf[i].w = bf16rne(f.w);
    }
  };
  auto commit = [&](unsigned short* dst) {
#pragma unroll
    for (int i = 0; i < 8; ++i) {
      const int v = t + i * 512;
      const int row = v >> 5;
      const int c8 = (v & 31) * 8;
      const int off = (row << 8) + (c8 ^ ((row & 15) << 4));
      *(ushort4*)((char*)dst + off) = pf[i];
    }
  };

  prefetch(b0);
  commit((unsigned short*)sSeq[0]);
  __syncthreads();

#pragma unroll 1
  for (int j = 0; j < BLOOP; ++j) {
    const int b = b0 + j;
    unsigned short* cSeq = (unsigned short*)sSeq[j & 1];
    unsigned short* nSeq = (unsigned short*)sSeq[(j & 1) ^ 1];

    if (j + 1 < BLOOP) prefetch(b + 1);

    float4 Tv[4];
#pragma unroll
    for (int mt = 0; mt < 4; ++mt)
      Tv[mt] = *(const float4*)(T + (size_t)b * NH + wh * 64 + mt * 16 + kq * 4);

    f32x4 acc[4][4];
#pragma unroll
    for (int mt = 0; mt < 4; ++mt)
#pragma unroll
      for (int nt = 0; nt < 4; ++nt) acc[mt][nt] = (f32x4){0.f, 0.f, 0.f, 0.f};

#pragma unroll
    for (int ks = 0; ks < 4; ++ks) {
      bf16x8 Bf[4];
#pragma unroll
      for (int nt = 0; nt < 4; ++nt) {
        const int row = wl * 64 + nt * 16 + lh;
        const int off = (row << 8) + (((ks << 6) + (kq << 4)) ^ ((row & 15) << 4));
        Bf[nt] = *(const bf16x8*)((const char*)cSeq + off);
      }
#pragma unroll
      for (int mt = 0; mt < 4; ++mt)
#pragma unroll
        for (int nt = 0; nt < 4; ++nt)
          acc[mt][nt] = __builtin_amdgcn_mfma_f32_16x16x32_bf16(
              a[ks][mt], Bf[nt], acc[mt][nt], 0, 0, 0);
    }
    __syncthreads();
    if (j + 1 < BLOOP) commit(nSeq);

    float p[4] = {0.f, 0.f, 0.f, 0.f};
#pragma unroll
    for (int mt = 0; mt < 4; ++mt) {
#pragma unroll
      for (int nt = 0; nt < 4; ++nt) {
        float z;
        z = acc[mt][nt][0] + Tv[mt].x + b1v[mt].x; p[nt] = fmaf(fmaxf(z, 0.f), wv[mt].x, p[nt]);
        z = acc[mt][nt][1] + Tv[mt].y + b1v[mt].y; p[nt] = fmaf(fmaxf(z, 0.f), wv[mt].y, p[nt]);
        z = acc[mt][nt][2] + Tv[mt].z + b1v[mt].z; p[nt] = fmaf(fmaxf(z, 0.f), wv[mt].z, p[nt]);
        z = acc[mt][nt][3] + Tv[mt].w + b1v[mt].w; p[nt] = fmaf(fmaxf(z, 0.f), wv[mt].w, p[nt]);
      }
    }
#pragma unroll
    for (int nt = 0; nt < 4; ++nt) {
      float v = p[nt];
      v += __shfl_xor(v, 16);
      v += __shfl_xor(v, 32);
      if (lane < 16) sRed[wh][wl * 64 + nt * 16 + lane] = v;
    }
    __syncthreads();
    if (t < 128) {
      const int l = l0 + t;
      float sc = sRed[0][t] + sRed[1][t] + sRed[2][t] + sRed[3][t] + b2v;
      if (mask[(size_t)b * NL + l] == 0) sc = MASK_FILL_F;
      scores[(size_t)b * NL + l] = sc;
    }
  }
}

// ---------- fused: histogram topM + LDS-staged exact rescore + select ----------
__global__ __launch_bounds__(1024, 4) void k_select3(
    const float* __restrict__ scores, const float* __restrict__ seq,
    const int* __restrict__ mask, const float* __restrict__ W1,
    const float* __restrict__ w2, const float* __restrict__ b2,
    const float* __restrict__ P, const float* __restrict__ T,
    int* __restrict__ idx_sorted, float* __restrict__ attn) {
  const int b = blockIdx.x, t = threadIdx.x;
  __shared__ float s_stage[128 * ND];   // 64 KB; phase A aliases hist here
  unsigned* hist = (unsigned*)s_stage;  // 4096 uints
  __shared__ unsigned chunk[256];
  __shared__ int sB;
  __shared__ unsigned sCntHi, sCntB, sN;
  __shared__ int s_cand[MCAP];
  __shared__ float s_cs[MCAP];
  __shared__ unsigned long long s_key[MCAP];
  __shared__ int sel_l[NK];
  __shared__ float sel_v[NK];
  __shared__ int srt_l[NK];
  __shared__ float srt_v[NK];

  for (int i = t; i < 4096; i += 1024) hist[i] = 0;
  if (t == 0) { sCntHi = 0; sCntB = 0; }
  __syncthreads();
  unsigned key2[2];
#pragma unroll
  for (int i = 0; i < 2; ++i) {
    unsigned u = __float_as_uint(scores[(size_t)b * NL + t + i * 1024]);
    u = (u & 0x80000000u) ? ~u : (u | 0x80000000u);
    key2[i] = u;
    atomicAdd(&hist[u >> 20], 1u);
  }
  __syncthreads();
  if (t < 256) {
    unsigned s = 0;
#pragma unroll 4
    for (int j = 0; j < 16; ++j) s += hist[t * 16 + j];
    chunk[t] = s;
  }
  __syncthreads();
  if (t == 0) {
    unsigned cum = 0;
    int c = 255;
    for (; c > 0; --c) {
      if (cum + chunk[c] >= (unsigned)HTHR) break;
      cum += chunk[c];
    }
    int bin = c * 16 + 15;
    for (; bin > c * 16; --bin) {
      if (cum + hist[bin] >= (unsigned)HTHR) break;
      cum += hist[bin];
    }
    sB = bin;
  }
  __syncthreads();
  const unsigned B = (unsigned)sB;
#pragma unroll
  for (int i = 0; i < 2; ++i) {
    if ((key2[i] >> 20) > B) {
      unsigned pos = atomicAdd(&sCntHi, 1u);
      s_cand[pos] = t + i * 1024;
    }
  }
  __syncthreads();
  const unsigned hi = sCntHi;
#pragma unroll
  for (int i = 0; i < 2; ++i) {
    if ((key2[i] >> 20) == B) {
      unsigned pos = atomicAdd(&sCntB, 1u);
      if (hi + pos < (unsigned)MCAP) s_cand[hi + pos] = t + i * 1024;
    }
  }
  __syncthreads();
  if (t == 0) {
    unsigned n = sCntHi + sCntB;
    sN = (n < (unsigned)MCAP) ? n : (unsigned)MCAP;
  }
  __syncthreads();
  const int n = (int)sN;

  const int hg = t & 63;
  const int rg = t >> 6;
  const float4* Wp = (const float4*)W1;
  const float4 wvq = ((const float4*)w2)[hg];
  const float4 Tvq = ((const float4*)(T + (size_t)b * NH))[hg];
  const float b2v = b2[0];
#pragma unroll 1
  for (int pass = 0; pass < 2; ++pass) {
    const int base = pass * 128;
    if (base >= n) break;
    __syncthreads();
#pragma unroll
    for (int i = 0; i < 4; ++i) {
      const int v = t + i * 1024;
      const int r = v >> 5, c = v & 31;
      const int slot = base + r;
      const int l = (slot < n) ? s_cand[slot] : 0;
      ((float4*)s_stage)[r * 32 + c] =
          ((const float4*)(seq + ((size_t)b * NL + l) * ND))[c];
    }
    __syncthreads();

    float acc[8][4];
#pragma unroll
    for (int r = 0; r < 8; ++r)
#pragma unroll
      for (int j = 0; j < 4; ++j) acc[r][j] = 0.0f;

    for (int d0 = 0; d0 < ND; d0 += 4) {
      float4 wq[4];
#pragma unroll
      for (int j = 0; j < 4; ++j) wq[j] = Wp[(size_t)(d0 + j) * (NH / 4) + hg];
#pragma unroll
      for (int r = 0; r < 8; ++r) {
        const float4 s = *(const float4*)&s_stage[(rg * 8 + r) * ND + d0];
        const float sv[4] = {s.x, s.y, s.z, s.w};
#pragma unroll
        for (int j = 0; j < 4; ++j) {
          acc[r][0] = fmaf(sv[j], wq[j].x, acc[r][0]);
          acc[r][1] = fmaf(sv[j], wq[j].y, acc[r][1]);
          acc[r][2] = fmaf(sv[j], wq[j].z, acc[r][2]);
          acc[r][3] = fmaf(sv[j], wq[j].w, acc[r][3]);
        }
      }
    }

#pragma unroll
    for (int r = 0; r < 8; ++r) {
      const int slot = base + rg * 8 + r;
      const int l = (slot < n) ? s_cand[slot] : 0;
      const float4 Pv = ((const float4*)(P + (size_t)l * NH))[hg];
      float z, p = 0.0f;
      z = acc[r][0] + Pv.x + Tvq.x; p = fmaf(fmaxf(z, 0.0f), wvq.x, p);
      z = acc[r][1] + Pv.y + Tvq.y; p = fmaf(fmaxf(z, 0.0f), wvq.y, p);
      z = acc[r][2] + Pv.z + Tvq.z; p = fmaf(fmaxf(z, 0.0f), wvq.z, p);
      z = acc[r][3] + Pv.w + Tvq.w; p = fmaf(fmaxf(z, 0.0f), wvq.w, p);
#pragma unroll
      for (int off = 32; off >= 1; off >>= 1) p += __shfl_xor(p, off);
      if (hg == 0 && slot < n) {
        float sc = p + b2v;
        if (mask[(size_t)b * NL + l] == 0) sc = MASK_FILL_F;
        s_cs[slot] = sc;
      }
    }
  }
  __syncthreads();

  for (int s = t; s < MCAP; s += 1024) {
    unsigned long long kk = 0ull;
    if (s < n) {
      unsigned u = __float_as_uint(s_cs[s]);
      u = (u & 0x80000000u) ? ~u : (u | 0x80000000u);
      const int l = s_cand[s];
      kk = ((unsigned long long)u << 11) | (unsigned long long)(NL - 1 - l);
    }
    s_key[s] = kk;
  }
  __syncthreads();
  for (int s = t; s < MCAP; s += 1024) {
    if (s < n) {
      const unsigned long long mk = s_key[s];
      int rank = 0;
      for (int j = 0; j < n; ++j) rank += (s_key[j] > mk) ? 1 : 0;
      if (rank < NK) {
        sel_l[rank] = (NL - 1) - (int)(mk & 0x7FFull);
        sel_v[rank] = s_cs[s];
      }
    }
  }
  __syncthreads();
  if (t < NK) {
    const int myl = sel_l[t];
    int pos = 0;
#pragma unroll 8
    for (int j = 0; j < NK; ++j) pos += (sel_l[j] < myl) ? 1 : 0;
    srt_l[pos] = myl;
    srt_v[pos] = sel_v[t];
  }
  __syncthreads();
  if (t < 64) {
    const float sc = srt_v[t];
    float m = sc;
#pragma unroll
    for (int off = 32; off >= 1; off >>= 1) m = fmaxf(m, __shfl_xor(m, off));
    const float e = expf(sc - m);
    float s = e;
#pragma unroll
    for (int off = 32; off >= 1; off >>= 1) s += __shfl_xor(s, off);
    attn[(size_t)b * NK + t] = e / s;
    idx_sorted[(size_t)b * NK + t] = srt_l[t];
  }
}

// ---------- MFMA encoder: gather -> enc1 -> enc2 -> pool -> LN ----------
// 1 block/batch, 512 thr (8 waves). bf16 MFMA (error ~1e-2 << 0.065 thr).
__global__ __launch_bounds__(512, 2) void k_encode(
    const float* __restrict__ seq, const float* __restrict__ pos,
    const int* __restrict__ idx_sorted, const float* __restrict__ attn_g,
    const unsigned short* __restrict__ We1T, const float* __restrict__ be1,
    const unsigned short* __restrict__ We2T, const float* __restrict__ be2,
    const float* __restrict__ gamma, const float* __restrict__ beta,
    float* __restrict__ out) {
  const int b = blockIdx.x, t = threadIdx.x;
  const int lane = t & 63, w = t >> 6;
  const int lh = lane & 15, kq = lane >> 4;
  __shared__ unsigned short s_in[64 * 256];  // 32 KB, 512B rows, swizzled
  __shared__ unsigned short s_h1[64 * 256];  // 32 KB, same layout
  __shared__ float red[4][128];
  __shared__ float rr[4];
  __shared__ int s_idx[NK];
  __shared__ float s_at[NK];

  if (t < NK) {
    s_idx[t] = idx_sorted[(size_t)b * NK + t];
    s_at[t] = attn_g[(size_t)b * NK + t];
  }
  __syncthreads();

  // gather [seq|pos] rows -> bf16 swizzled LDS (4096 ushort4, 8/thread)
#pragma unroll
  for (int i = 0; i < 8; ++i) {
    const int v = t + i * 512;
    const int row = v >> 6;   // 64 ushort4 per 512B row
    const int q = v & 63;
    const int idx = s_idx[row];
    float4 f;
    if (q < 32) f = ((const float4*)(seq + ((size_t)b * NL + idx) * ND))[q];
    else        f = ((const float4*)(pos + (size_t)idx * ND))[q - 32];
    ushort4 hv;
    hv.x = bf16rne(f.x); hv.y = bf16rne(f.y);
    hv.z = bf16rne(f.z); hv.w = bf16rne(f.w);
    const int off = (row << 9) + ((q * 8) ^ ((row & 15) << 4));
    *(ushort4*)((char*)s_in + off) = hv;
  }
  __syncthreads();

  // MFMA1: z[h, row] over K=256; waves (wh 0..3) x (wn 0..1)
  {
    const int wh = w & 3, wn = w >> 2;
    f32x4 acc1[4][2];
#pragma unroll
    for (int mt = 0; mt < 4; ++mt)
#pragma unroll
      for (int nt = 0; nt < 2; ++nt) acc1[mt][nt] = (f32x4){0.f, 0.f, 0.f, 0.f};
#pragma unroll
    for (int ks = 0; ks < 8; ++ks) {
      bf16x8 Bf[2];
#pragma unroll
      for (int nt = 0; nt < 2; ++nt) {
        const int row = wn * 32 + nt * 16 + lh;
        const int off = (row << 9) + ((ks * 64 + kq * 16) ^ ((row & 15) << 4));
        Bf[nt] = *(const bf16x8*)((const char*)s_in + off);
      }
#pragma unroll
      for (int mt = 0; mt < 4; ++mt) {
        const bf16x8 Af = *(const bf16x8*)(
            We1T + (size_t)(wh * 64 + mt * 16 + lh) * 256 + ks * 32 + kq * 8);
#pragma unroll
        for (int nt = 0; nt < 2; ++nt)
          acc1[mt][nt] = __builtin_amdgcn_mfma_f32_16x16x32_bf16(
              Af, Bf[nt], acc1[mt][nt], 0, 0, 0);
      }
    }
    // relu(z + be1) -> bf16 -> s_h1 (swizzled)
#pragma unroll
    for (int mt = 0; mt < 4; ++mt) {
      const int h0 = wh * 64 + mt * 16 + kq * 4;
      const float4 bv = *(const float4*)(be1 + h0);
#pragma unroll
      for (int nt = 0; nt < 2; ++nt) {
        const int row = wn * 32 + nt * 16 + lh;
        const float z0 = fmaxf(acc1[mt][nt][0] + bv.x, 0.0f);
        const float z1 = fmaxf(acc1[mt][nt][1] + bv.y, 0.0f);
        const float z2 = fmaxf(acc1[mt][nt][2] + bv.z, 0.0f);
        const float z3 = fmaxf(acc1[mt][nt][3] + bv.w, 0.0f);
        const unsigned u0 = (unsigned)bf16rne(z0) | ((unsigned)bf16rne(z1) << 16);
        const unsigned u1 = (unsigned)bf16rne(z2) | ((unsigned)bf16rne(z3) << 16);
        const int off = (row << 9) + ((h0 * 2) ^ ((row & 15) << 4));
        *(unsigned*)((char*)s_h1 + off) = u0;
        *(unsigned*)((char*)s_h1 + off + 4) = u1;
      }
    }
  }
  __syncthreads();

  // MFMA2: enc2 over K=256h; waves (wo 0..1) x (wn4 0..3); +attn pool
  {
    const int wo = w & 1, wn4 = w >> 1;
    const int row = wn4 * 16 + lh;
    f32x4 acc2[4];
#pragma unroll
    for (int mt = 0; mt < 4; ++mt) acc2[mt] = (f32x4){0.f, 0.f, 0.f, 0.f};
#pragma unroll
    for (int ks = 0; ks < 8; ++ks) {
      const int off = (row << 9) + ((ks * 64 + kq * 16) ^ ((row & 15) << 4));
      const bf16x8 Bf = *(const bf16x8*)((const char*)s_h1 + off);
#pragma unroll
      for (int mt = 0; mt < 4; ++mt) {
        const bf16x8 Af = *(const bf16x8*)(
            We2T + (size_t)(wo * 64 + mt * 16 + lh) * 256 + ks * 32 + kq * 8);
        acc2[mt] = __builtin_amdgcn_mfma_f32_16x16x32_bf16(Af, Bf, acc2[mt], 0, 0, 0);
      }
    }
    const float at = s_at[row];
#pragma unroll
    for (int mt = 0; mt < 4; ++mt) {
#pragma unroll
      for (int j = 0; j < 4; ++j) {
        float v = acc2[mt][j] * at;
        v += __shfl_xor(v, 1);
        v += __shfl_xor(v, 2);
        v += __shfl_xor(v, 4);
        v += __shfl_xor(v, 8);
        if (lh == 0) red[wn4][wo * 64 + mt * 16 + kq * 4 + j] = v;
      }
    }
  }
  __syncthreads();

  // pooled = sum partials + be2 (sum(attn)=1), then LN
  float pooled = 0.0f;
  if (t < NO)
    pooled = red[0][t] + red[1][t] + red[2][t] + red[3][t] + be2[t];
  float s1 = (t < NO) ? pooled : 0.0f;
  float s2 = (t < NO) ? pooled * pooled : 0.0f;
#pragma unroll
  for (int off = 32; off >= 1; off >>= 1) {
    s1 += __shfl_xor(s1, off);
    s2 += __shfl_xor(s2, off);
  }
  if (t < NO && (t & 63) == 0) {
    rr[(t >> 6) * 2] = s1;
    rr[(t >> 6) * 2 + 1] = s2;
  }
  __syncthreads();
  if (t < NO) {
    const float S1 = rr[0] + rr[2];
    const float S2 = rr[1] + rr[3];
    const float mu = S1 / NO;
    const float var = S2 / NO - mu * mu;
    const float rs = rsqrtf(var + LN_EPS_F);
    out[(size_t)b * NO + t] = (pooled - mu) * rs * gamma[t] + beta[t];
  }
}

extern "C" void kernel_launch(void* const* d_in, const int* in_sizes, int n_in,
                              void* d_out, int out_size, void* d_ws, size_t ws_size,
                              hipStream_t stream) {
  (void)in_sizes; (void)n_in; (void)out_size; (void)ws_size;
  const float* seq = (const float*)d_in[0];
  const int* mask = (const int*)d_in[1];
  const float* tgt = (const float*)d_in[2];
  const float* pos = (const float*)d_in[3];
  const float* W1 = (const float*)d_in[4];
  const float* b1 = (const float*)d_in[5];
  const float* w2 = (const float*)d_in[6];
  const float* b2 = (const float*)d_in[7];
  const float* We1 = (const float*)d_in[8];
  const float* be1 = (const float*)d_in[9];
  const float* We2 = (const float*)d_in[10];
  const float* be2 = (const float*)d_in[11];
  const float* gam = (const float*)d_in[12];
  const float* bet = (const float*)d_in[13];
  float* out = (float*)d_out;

  float* P = (float*)d_ws;                            // NL*NH
  float* T = P + (size_t)NL * NH;                     // NB*NH
  float* scores = T + (size_t)NB * NH;                // NB*NL
  float* attn = scores + (size_t)NB * NL;             // NB*NK
  int* idxs = (int*)(attn + (size_t)NB * NK);         // NB*NK
  unsigned short* w1aT = (unsigned short*)(idxs + (size_t)NB * NK);  // NH*ND
  unsigned short* we1T = w1aT + (size_t)NH * ND;      // 256*256
  unsigned short* we2T = we1T + (size_t)256 * 256;    // 128*256

  k_prep<<<ND + NL + NB + 512, 256, 0, stream>>>(W1, pos, tgt, b1, We1, We2,
                                                 w1aT, P, T, we1T, we2T);
  k_scores_mfma<<<dim3(NL / 128, NB / BLOOP), 512, 0, stream>>>(
      seq, mask, w1aT, w2, b2, b1, T, scores);
  k_select3<<<NB, 1024, 0, stream>>>(scores, seq, mask, W1, w2, b2, P, T,
                                     idxs, attn);
  k_encode<<<NB, 512, 0, stream>>>(seq, pos, idxs, attn, we1T, be1, we2T, be2,
                                   gam, bet, out);
}